// Round 1
// baseline (348.486 us; speedup 1.0000x reference)
//
#include <hip/hip_runtime.h>
#include <math.h>

// Problem constants (fixed by reference)
#define BB 4096
#define N_ELEC 64
#define N_NUC 16
#define FF 128
#define CUTOFF 5.0f

typedef float v4f __attribute__((ext_vector_type(4)));

static constexpr long long S_SIZE = (long long)BB * N_NUC * FF;        // 8388608 floats
static constexpr long long V_SIZE = (long long)BB * N_NUC * 3 * FF;    // 25165824
static constexpr long long E_CNT  = (long long)BB * N_NUC * N_ELEC;    // 4194304

static constexpr long long OFF_EI = S_SIZE + V_SIZE;       // row; col at +E_CNT
static constexpr long long OFF_EA = OFF_EI + 2 * E_CNT;
static constexpr long long OFF_M  = OFF_EA + 3 * E_CNT;
// total = 58720256 floats = 224 MiB

static constexpr long long S4 = S_SIZE / 4;                // 2097152 v4f
static constexpr long long V4 = V_SIZE / 4;                // 6291456 v4f

// Grid layout: [0, EDGE_BLOCKS) edge blocks (1 batch each, 4 edges/thread),
//              [EDGE_BLOCKS, +COPY_BLOCKS) copy blocks (4 v4f/thread).
static constexpr int EDGE_BLOCKS = BB;                              // 4096
static constexpr int COPY_BLOCKS = (int)((S4 + V4) / 1024);         // 8192
static constexpr int S_COPY_BLOCKS = (int)(S4 / 1024);              // 2048 (exact)

__global__ __launch_bounds__(256) void fused_kernel(
    const v4f* __restrict__ s, const v4f* __restrict__ v,
    const float* __restrict__ coord_elec,   // [B, 64, 3]
    const float* __restrict__ coord_nuc,    // [16, 3]
    float* __restrict__ out)
{
    const int bid = blockIdx.x;
    const int t = threadIdx.x;

    if (bid >= EDGE_BLOCKS) {
        // ---- copy path: 4 x 16B per thread, cached loads, NT stores ----
        const int cb = bid - EDGE_BLOCKS;
        const long long g = (long long)cb * 1024 + t;   // global v4f index
        // Block-uniform source select (scalar branch on blockIdx-derived cb).
        const v4f* __restrict__ src = (cb < S_COPY_BLOCKS) ? (s + g) : (v + (g - S4));
        v4f a0 = src[0];
        v4f a1 = src[256];
        v4f a2 = src[512];
        v4f a3 = src[768];
        v4f* dst = (v4f*)out + g;
        __builtin_nontemporal_store(a0, dst);
        __builtin_nontemporal_store(a1, dst + 256);
        __builtin_nontemporal_store(a2, dst + 512);
        __builtin_nontemporal_store(a3, dst + 768);
        return;
    }

    // ---- edge path: one block per batch b, 1024 edges, 4 edges/thread ----
    __shared__ float nuc[N_NUC * 3];      // 48
    __shared__ float elec[N_ELEC * 3];    // 192

    const int b = bid;
    if (t < 48) nuc[t] = coord_nuc[t];
    if (t >= 64 && t < 64 + 192)
        elec[t - 64] = coord_elec[(long long)b * (N_ELEC * 3) + (t - 64)];
    __syncthreads();

    const int i  = t >> 4;            // nuc index 0..15
    const int j0 = (t & 15) << 2;     // first elec index 0,4,...,60
    const long long e = (long long)b * 1024 + ((long long)t << 2);

    const float nx = nuc[i * 3 + 0];
    const float ny = nuc[i * 3 + 1];
    const float nz = nuc[i * 3 + 2];

    float d[4][3];
    v4f msk;
    #pragma unroll
    for (int k = 0; k < 4; ++k) {
        const float dx = elec[(j0 + k) * 3 + 0] - nx;
        const float dy = elec[(j0 + k) * 3 + 1] - ny;
        const float dz = elec[(j0 + k) * 3 + 2] - nz;
        d[k][0] = dx; d[k][1] = dy; d[k][2] = dz;
        const float dist = sqrtf(dx * dx + dy * dy + dz * dz);
        msk[k] = dist < CUTOFF ? 1.0f : 0.0f;
    }

    const float rowf = (float)(b * N_NUC + i);
    const v4f row = {rowf, rowf, rowf, rowf};
    const float c0 = (float)(b * N_ELEC + j0);
    const v4f col = {c0, c0 + 1.0f, c0 + 2.0f, c0 + 3.0f};

    __builtin_nontemporal_store(row, (v4f*)(out + OFF_EI + e));
    __builtin_nontemporal_store(col, (v4f*)(out + OFF_EI + E_CNT + e));
    __builtin_nontemporal_store(msk, (v4f*)(out + OFF_M + e));

    const v4f a0 = {d[0][0], d[0][1], d[0][2], d[1][0]};
    const v4f a1 = {d[1][1], d[1][2], d[2][0], d[2][1]};
    const v4f a2 = {d[2][2], d[3][0], d[3][1], d[3][2]};
    v4f* ap = (v4f*)(out + OFF_EA + e * 3);
    __builtin_nontemporal_store(a0, ap + 0);
    __builtin_nontemporal_store(a1, ap + 1);
    __builtin_nontemporal_store(a2, ap + 2);
}

extern "C" void kernel_launch(void* const* d_in, const int* in_sizes, int n_in,
                              void* d_out, int out_size, void* d_ws, size_t ws_size,
                              hipStream_t stream) {
    const float* s_nuc      = (const float*)d_in[0];
    const float* v_nuc      = (const float*)d_in[1];
    const float* coord_elec = (const float*)d_in[2];
    const float* coord_nuc  = (const float*)d_in[3];
    float* out = (float*)d_out;

    fused_kernel<<<EDGE_BLOCKS + COPY_BLOCKS, 256, 0, stream>>>(
        (const v4f*)s_nuc, (const v4f*)v_nuc, coord_elec, coord_nuc, out);
}

// Round 2
// 326.212 us; speedup vs baseline: 1.0683x; 1.0683x over previous
//
#include <hip/hip_runtime.h>
#include <math.h>

// Problem constants (fixed by reference)
#define BB 4096
#define N_ELEC 64
#define N_NUC 16
#define FF 128
#define CUTOFF 5.0f

// Native clang vector type — accepted by __builtin_nontemporal_{load,store}
typedef float v4f __attribute__((ext_vector_type(4)));

static constexpr long long S_SIZE = (long long)BB * N_NUC * FF;        // 8388608
static constexpr long long V_SIZE = (long long)BB * N_NUC * 3 * FF;    // 25165824
static constexpr long long E_CNT  = (long long)BB * N_NUC * N_ELEC;    // 4194304

static constexpr long long OFF_EI = S_SIZE + V_SIZE;       // 33554432 (row; col at +E_CNT)
static constexpr long long OFF_EA = OFF_EI + 2 * E_CNT;    // 41943040
static constexpr long long OFF_M  = OFF_EA + 3 * E_CNT;    // 54525952
// total = 58720256 floats = 224 MiB

static constexpr int COPY_BLOCKS = (int)((S_SIZE + V_SIZE) / 4 / 256); // 32768
static constexpr int EDGE_BLOCKS = (int)(E_CNT / 256);                 // 16384

// ---------------------------------------------------------------------------
// Round-0 structure (fastest measured: 318.8 us), ONE controlled change:
// copy-path loads are CACHED (plain) instead of nontemporal. Inputs (134 MB)
// are L3-resident across graph iterations; the NT hint was discouraging
// retention. Stores stay NT (zero reuse, 224 MiB stream).
//   blocks [0, COPY_BLOCKS)                : v4f copy of s_nuc + v_nuc
//   blocks [COPY_BLOCKS, +EDGE_BLOCKS)     : 256 edges each
// Each edge block lies fully inside one batch b (256 | 1024 edges per b).
// edge_attr is staged in LDS and written out as coalesced 16B stores.
// ---------------------------------------------------------------------------
__global__ __launch_bounds__(256) void fused_kernel(
    const v4f* __restrict__ s, const v4f* __restrict__ v,
    const float* __restrict__ coord_elec,   // [B, 64, 3]
    const float* __restrict__ coord_nuc,    // [16, 3]
    float* __restrict__ out)
{
    const int bid = blockIdx.x;
    const int t = threadIdx.x;

    if (bid < COPY_BLOCKS) {
        long long i = (long long)bid * 256 + t;
        constexpr long long S4 = S_SIZE / 4;  // 2097152
        v4f val = (i < S4) ? s[i] : v[i - S4];          // cached loads
        __builtin_nontemporal_store(val, &((v4f*)out)[i]);
        return;
    }

    // ---- edge path ----
    __shared__ float nuc[N_NUC * 3];      // 48
    __shared__ float elec[N_ELEC * 3];    // 192
    __shared__ float attr[256 * 3];       // 768

    const long long e0 = (long long)(bid - COPY_BLOCKS) * 256;
    const int b = (int)(e0 >> 10);        // batch index, uniform per block

    if (t < 48) nuc[t] = coord_nuc[t];
    if (t >= 64 && t < 64 + 192)
        elec[t - 64] = coord_elec[(long long)b * (N_ELEC * 3) + (t - 64)];
    __syncthreads();

    const long long e = e0 + t;
    const int i = (int)((e >> 6) & 15);   // nuc index
    const int j = t & 63;                 // elec index

    float d0 = elec[j * 3 + 0] - nuc[i * 3 + 0];
    float d1 = elec[j * 3 + 1] - nuc[i * 3 + 1];
    float d2 = elec[j * 3 + 2] - nuc[i * 3 + 2];

    attr[t * 3 + 0] = d0;
    attr[t * 3 + 1] = d1;
    attr[t * 3 + 2] = d2;

    // edge_index (row, col) + mask — lane-contiguous scalar stores (coalesced)
    __builtin_nontemporal_store((float)(b * N_NUC + i),  &out[OFF_EI + e]);
    __builtin_nontemporal_store((float)(b * N_ELEC + j), &out[OFF_EI + E_CNT + e]);
    float dist = sqrtf(d0 * d0 + d1 * d1 + d2 * d2);
    __builtin_nontemporal_store(dist < CUTOFF ? 1.0f : 0.0f, &out[OFF_M + e]);

    __syncthreads();

    // edge_attr for this block's 256 edges: 768 floats = 192 16B-stores, coalesced
    if (t < 192) {
        v4f* dst = (v4f*)(out + OFF_EA + e0 * 3);
        __builtin_nontemporal_store(((const v4f*)attr)[t], &dst[t]);
    }
}

extern "C" void kernel_launch(void* const* d_in, const int* in_sizes, int n_in,
                              void* d_out, int out_size, void* d_ws, size_t ws_size,
                              hipStream_t stream) {
    const float* s_nuc      = (const float*)d_in[0];
    const float* v_nuc      = (const float*)d_in[1];
    const float* coord_elec = (const float*)d_in[2];
    const float* coord_nuc  = (const float*)d_in[3];
    float* out = (float*)d_out;

    fused_kernel<<<COPY_BLOCKS + EDGE_BLOCKS, 256, 0, stream>>>(
        (const v4f*)s_nuc, (const v4f*)v_nuc, coord_elec, coord_nuc, out);
}

// Round 3
// 319.565 us; speedup vs baseline: 1.0905x; 1.0208x over previous
//
#include <hip/hip_runtime.h>
#include <math.h>

// Problem constants (fixed by reference)
#define BB 4096
#define N_ELEC 64
#define N_NUC 16
#define FF 128
#define CUTOFF 5.0f

// Native clang vector type — accepted by __builtin_nontemporal_{load,store}
typedef float v4f __attribute__((ext_vector_type(4)));

static constexpr long long S_SIZE = (long long)BB * N_NUC * FF;        // 8388608
static constexpr long long V_SIZE = (long long)BB * N_NUC * 3 * FF;    // 25165824
static constexpr long long E_CNT  = (long long)BB * N_NUC * N_ELEC;    // 4194304

static constexpr long long OFF_EI = S_SIZE + V_SIZE;       // 33554432 (row; col at +E_CNT)
static constexpr long long OFF_EA = OFF_EI + 2 * E_CNT;    // 41943040
static constexpr long long OFF_M  = OFF_EA + 3 * E_CNT;    // 54525952
// total = 58720256 floats = 224 MiB

static constexpr int COPY_BLOCKS = (int)((S_SIZE + V_SIZE) / 4 / 256); // 32768
static constexpr int EDGE_BLOCKS = (int)(E_CNT / 256);                 // 16384

// ---------------------------------------------------------------------------
// BEST-MEASURED STRUCTURE (318.8 us; verified twice across sessions).
// Per-iteration cost decomposition (rocprof): 2x harness poison-fill
// dispatches ~143-147 us each (940 MB @ ~6.5 TB/s, HBM-bound, not ours)
// = ~289 us fixed; this kernel ~30 us (369 MB at ~12-13 TB/s — L3-absorbed,
// above HBM roofline). Measured variants:
//   - NT loads + NT stores (this):           318.8 us   <- best
//   - cached loads + NT stores:              326.2 us   (input stream pollutes
//     the cache capacity the 224 MiB NT write stream wants)
//   - restructured copy/edge (4 edges/thr):  348.5 us   (48B-stride attr
//     stores scatter partial cachelines)
//   blocks [0, COPY_BLOCKS)                : v4f copy of s_nuc + v_nuc
//   blocks [COPY_BLOCKS, +EDGE_BLOCKS)     : 256 edges each
// Each edge block lies fully inside one batch b (256 | 1024 edges per b).
// edge_attr is staged in LDS and written out as coalesced 16B stores.
// All output stores are nontemporal (zero reuse, 224 MiB stream).
// ---------------------------------------------------------------------------
__global__ __launch_bounds__(256) void fused_kernel(
    const v4f* __restrict__ s, const v4f* __restrict__ v,
    const float* __restrict__ coord_elec,   // [B, 64, 3]
    const float* __restrict__ coord_nuc,    // [16, 3]
    float* __restrict__ out)
{
    const int bid = blockIdx.x;
    const int t = threadIdx.x;

    if (bid < COPY_BLOCKS) {
        long long i = (long long)bid * 256 + t;
        constexpr long long S4 = S_SIZE / 4;  // 2097152
        v4f val = (i < S4) ? __builtin_nontemporal_load(&s[i])
                           : __builtin_nontemporal_load(&v[i - S4]);
        __builtin_nontemporal_store(val, &((v4f*)out)[i]);
        return;
    }

    // ---- edge path ----
    __shared__ float nuc[N_NUC * 3];      // 48
    __shared__ float elec[N_ELEC * 3];    // 192
    __shared__ float attr[256 * 3];       // 768

    const long long e0 = (long long)(bid - COPY_BLOCKS) * 256;
    const int b = (int)(e0 >> 10);        // batch index, uniform per block

    if (t < 48) nuc[t] = coord_nuc[t];
    if (t >= 64 && t < 64 + 192)
        elec[t - 64] = coord_elec[(long long)b * (N_ELEC * 3) + (t - 64)];
    __syncthreads();

    const long long e = e0 + t;
    const int i = (int)((e >> 6) & 15);   // nuc index
    const int j = t & 63;                 // elec index

    float d0 = elec[j * 3 + 0] - nuc[i * 3 + 0];
    float d1 = elec[j * 3 + 1] - nuc[i * 3 + 1];
    float d2 = elec[j * 3 + 2] - nuc[i * 3 + 2];

    attr[t * 3 + 0] = d0;
    attr[t * 3 + 1] = d1;
    attr[t * 3 + 2] = d2;

    // edge_index (row, col) + mask — lane-contiguous scalar stores (coalesced)
    __builtin_nontemporal_store((float)(b * N_NUC + i),  &out[OFF_EI + e]);
    __builtin_nontemporal_store((float)(b * N_ELEC + j), &out[OFF_EI + E_CNT + e]);
    float dist = sqrtf(d0 * d0 + d1 * d1 + d2 * d2);
    __builtin_nontemporal_store(dist < CUTOFF ? 1.0f : 0.0f, &out[OFF_M + e]);

    __syncthreads();

    // edge_attr for this block's 256 edges: 768 floats = 192 16B-stores, coalesced
    if (t < 192) {
        v4f* dst = (v4f*)(out + OFF_EA + e0 * 3);
        __builtin_nontemporal_store(((const v4f*)attr)[t], &dst[t]);
    }
}

extern "C" void kernel_launch(void* const* d_in, const int* in_sizes, int n_in,
                              void* d_out, int out_size, void* d_ws, size_t ws_size,
                              hipStream_t stream) {
    const float* s_nuc      = (const float*)d_in[0];
    const float* v_nuc      = (const float*)d_in[1];
    const float* coord_elec = (const float*)d_in[2];
    const float* coord_nuc  = (const float*)d_in[3];
    float* out = (float*)d_out;

    fused_kernel<<<COPY_BLOCKS + EDGE_BLOCKS, 256, 0, stream>>>(
        (const v4f*)s_nuc, (const v4f*)v_nuc, coord_elec, coord_nuc, out);
}